// Round 4
// baseline (1273.677 us; speedup 1.0000x reference)
//
#include <hip/hip_runtime.h>

#define N_NODES 100000
#define N_EDGES 1024
#define C_DIM 128
#define EDGE_CAP 1280   // Binom(100000,0.01): mean 1000, sd 31.5 -> +8.9 sigma
#define NODE_CAP 64     // Binom(1024,0.01): mean 10.24 -> +16 sigma
#define STRIP_W 32      // 32 floats = 128 B = one cache line per row-segment
#define CHUNK_R 2048    // rows per block
#define LCAP 64         // per-block per-edge LDS list cap: mean 20.5, +9.7 sigma
#define EPS 1e-8f

// ---------------- zero the counters (ws is re-poisoned to 0xAA every call) ---
__global__ void k_zero(int* p, int n) {
    int i = blockIdx.x * 256 + threadIdx.x;
    if (i < n) p[i] = 0;
}

// ---------------- softmax over edge_attention + entropy (E=1024, 1 block) ---
__global__ void k_attn_entropy(const float* __restrict__ ea,
                               float* __restrict__ attn,
                               float* __restrict__ entropy) {
    __shared__ float red[17];
    int t = threadIdx.x;              // blockDim = 1024 = 16 waves
    float x = ea[t];

    float m = x;
    for (int o = 32; o > 0; o >>= 1) m = fmaxf(m, __shfl_xor(m, o));
    if ((t & 63) == 0) red[t >> 6] = m;
    __syncthreads();
    if (t == 0) { float a = red[0]; for (int i = 1; i < 16; i++) a = fmaxf(a, red[i]); red[16] = a; }
    __syncthreads();
    m = red[16];
    __syncthreads();

    float ex = expf(x - m);
    float s = ex;
    for (int o = 32; o > 0; o >>= 1) s += __shfl_xor(s, o);
    if ((t & 63) == 0) red[t >> 6] = s;
    __syncthreads();
    if (t == 0) { float a = 0; for (int i = 0; i < 16; i++) a += red[i]; red[16] = a; }
    __syncthreads();
    float S = red[16];
    __syncthreads();

    float a_t = ex / S;
    attn[t] = a_t;

    float T = a_t;
    for (int o = 32; o > 0; o >>= 1) T += __shfl_xor(T, o);
    if ((t & 63) == 0) red[t >> 6] = T;
    __syncthreads();
    if (t == 0) { float a = 0; for (int i = 0; i < 16; i++) a += red[i]; red[16] = a; }
    __syncthreads();
    T = red[16];
    __syncthreads();

    float p = a_t / (T + EPS);
    float ent = -p * logf(p + EPS);
    for (int o = 32; o > 0; o >>= 1) ent += __shfl_xor(ent, o);
    if ((t & 63) == 0) red[t >> 6] = ent;
    __syncthreads();
    if (t == 0) { float a = 0; for (int i = 0; i < 16; i++) a += red[i]; entropy[0] = a; }
}

// ------- strip scan: LDS-aggregated CSC build + direct CSR (u16), coalesced --
// grid = (NCHUNK, E/STRIP_W) [chunk-major: concurrent blocks hit different
// node rows]; block = 256. 4-row unrolled loads for memory-level parallelism.
__global__ __launch_bounds__(256) void k_scan(
        const float4* __restrict__ inc4,
        int* __restrict__ edge_cnt, int* __restrict__ ndeg,
        int* __restrict__ edge_nodes, unsigned short* __restrict__ node_edges) {
    __shared__ int lcnt[STRIP_W];
    __shared__ int lbase[STRIP_W];
    __shared__ int llist[STRIP_W * LCAP];
    int t = threadIdx.x;
    int e0 = blockIdx.y * STRIP_W;       // strip's first edge
    int row0 = blockIdx.x * CHUNK_R;
    if (t < STRIP_W) lcnt[t] = 0;
    __syncthreads();

    int rsub = t >> 3;                   // 0..31: row within 32-row group
    int seg  = t & 7;                    // 0..7: float4 within the 32-col strip
    int off  = (e0 >> 2) + seg;
    #pragma unroll 1
    for (int it = 0; it < CHUNK_R / 128; it++) {   // 16 iters x 128 rows
        int rA = row0 + it * 128 + rsub;
        int rB = rA + 32, rC = rA + 64, rD = rA + 96;
        float4 z = {0.f, 0.f, 0.f, 0.f};
        float4 vA = z, vB = z, vC = z, vD = z;
        // 4 independent loads issued before any use -> 4x latency hiding
        if (rA < N_NODES) vA = inc4[(size_t)rA * (N_EDGES / 4) + off];
        if (rB < N_NODES) vB = inc4[(size_t)rB * (N_EDGES / 4) + off];
        if (rC < N_NODES) vC = inc4[(size_t)rC * (N_EDGES / 4) + off];
        if (rD < N_NODES) vD = inc4[(size_t)rD * (N_EDGES / 4) + off];

        float4 vs[4] = {vA, vB, vC, vD};
        int    rs[4] = {rA, rB, rC, rD};
        #pragma unroll
        for (int j = 0; j < 4; j++) {
            float4 v = vs[j];
            int row = rs[j];
            if (v.x != 0.f || v.y != 0.f || v.z != 0.f || v.w != 0.f) {
                float vals[4] = {v.x, v.y, v.z, v.w};
                #pragma unroll
                for (int k = 0; k < 4; k++) {
                    if (vals[k] != 0.0f) {
                        int el = seg * 4 + k;                       // local edge 0..31
                        int p = atomicAdd(&lcnt[el], 1);            // LDS atomic: cheap
                        if (p < LCAP) llist[el * LCAP + p] = row;
                        int q = atomicAdd(&ndeg[row], 1);           // chunk-local rows
                        if (q < NODE_CAP)
                            node_edges[row * NODE_CAP + q] = (unsigned short)(e0 + el);
                    }
                }
            }
        }
    }
    __syncthreads();
    if (t < STRIP_W) {
        int c = lcnt[t];
        if (c > LCAP) { c = LCAP; lcnt[t] = LCAP; }
        lbase[t] = atomicAdd(&edge_cnt[e0 + t], c);   // ONE reservation per edge per block
    }
    __syncthreads();
    // coalesced copy-out of the per-edge lists
    for (int j = t; j < STRIP_W * LCAP; j += 256) {
        int el = j / LCAP;
        int k  = j - el * LCAP;
        if (k < lcnt[el]) {
            int dst = lbase[el] + k;
            if (dst < EDGE_CAP)
                edge_nodes[(e0 + el) * EDGE_CAP + dst] = llist[j];
        }
    }
}

// -------- per-edge: he0 = sum nf rows; he1 = (he0@W1+b1)*attn; he2 = he1@W2 --
__global__ __launch_bounds__(256) void k_edge(
        const float* __restrict__ nf, const int* __restrict__ edge_cnt,
        const int* __restrict__ edge_nodes,
        const float* __restrict__ W1, const float* __restrict__ b1,
        const float* __restrict__ W2, const float* __restrict__ attn,
        float* __restrict__ he_out, float* __restrict__ he2) {
    __shared__ float lds[8 * 128];
    __shared__ float row[128];
    int e = blockIdx.x;
    int t = threadIdx.x;
    int grp = t >> 5, ln = t & 31;       // 8 row-groups x 32 lanes (float4 = 128 ch)
    int cnt = edge_cnt[e]; if (cnt > EDGE_CAP) cnt = EDGE_CAP;
    const int* nl = edge_nodes + e * EDGE_CAP;

    float4 acc = {0.f, 0.f, 0.f, 0.f};
    int i = grp;
    // 4-way unrolled: 4 independent row loads in flight per iteration
    for (; i + 24 < cnt; i += 32) {
        int n0 = nl[i], n1 = nl[i + 8], n2 = nl[i + 16], n3 = nl[i + 24];
        float4 x0 = ((const float4*)(nf + n0 * C_DIM))[ln];
        float4 x1 = ((const float4*)(nf + n1 * C_DIM))[ln];
        float4 x2 = ((const float4*)(nf + n2 * C_DIM))[ln];
        float4 x3 = ((const float4*)(nf + n3 * C_DIM))[ln];
        acc.x += x0.x + x1.x + x2.x + x3.x;
        acc.y += x0.y + x1.y + x2.y + x3.y;
        acc.z += x0.z + x1.z + x2.z + x3.z;
        acc.w += x0.w + x1.w + x2.w + x3.w;
    }
    for (; i < cnt; i += 8) {
        int nd = nl[i];
        float4 x = ((const float4*)(nf + nd * C_DIM))[ln];
        acc.x += x.x; acc.y += x.y; acc.z += x.z; acc.w += x.w;
    }
    ((float4*)lds)[grp * 32 + ln] = acc;
    __syncthreads();
    if (t < 128) {
        float s = 0.f;
        #pragma unroll
        for (int g = 0; g < 8; g++) s += lds[g * 128 + t];
        row[t] = s;                                   // he0[e, t]
    }
    __syncthreads();

    float attn_e = attn[e];
    float h1 = 0.f;
    if (t < 128) {
        float s = b1[t];
        #pragma unroll 8
        for (int c = 0; c < 128; c++) s += row[c] * W1[c * 128 + t];
        h1 = s * attn_e;
        he_out[e * 128 + t] = h1;                     // "he" output (post-attn)
    }
    __syncthreads();
    if (t < 128) row[t] = h1;
    __syncthreads();
    if (t < 128) {
        float s = 0.f;
        #pragma unroll 8
        for (int c = 0; c < 128; c++) s += row[c] * W2[c * 128 + t];
        he2[e * 128 + t] = s;                         // he1 @ W2 (assoc. trick)
    }
}

// -------- per-node: out = sum he2[edges] + b2 + nf (residual); sqnorm; degmax
__global__ __launch_bounds__(256) void k_node(
        const float* __restrict__ nf, const int* __restrict__ ndeg,
        const unsigned short* __restrict__ node_edges, const float* __restrict__ he2,
        const float* __restrict__ b2,
        float* __restrict__ out_node, float* __restrict__ sqnorm,
        int* __restrict__ dmax) {
    int t = threadIdx.x;
    int nsub = t >> 5, ln = t & 31;       // 8 nodes/block, 32 lanes * float4
    int n = blockIdx.x * 8 + nsub;
    float dmx = 0.f;
    if (n < N_NODES) {
        int d = ndeg[n]; if (d > NODE_CAP) d = NODE_CAP;
        dmx = (float)d;
        const unsigned short* el = node_edges + n * NODE_CAP;

        float4 acc = {0.f, 0.f, 0.f, 0.f};
        for (int i = 0; i < d; i++) {
            int e = (int)el[i];
            float4 h = ((const float4*)(he2 + e * C_DIM))[ln];
            acc.x += h.x; acc.y += h.y; acc.z += h.z; acc.w += h.w;
        }
        float4 x  = ((const float4*)(nf + n * C_DIM))[ln];
        float4 bb = ((const float4*)b2)[ln];
        float4 o = {acc.x + bb.x + x.x, acc.y + bb.y + x.y,
                    acc.z + bb.z + x.z, acc.w + bb.w + x.w};
        ((float4*)(out_node + n * C_DIM))[ln] = o;

        float sq = x.x * x.x + x.y * x.y + x.z * x.z + x.w * x.w;
        for (int o2 = 16; o2 > 0; o2 >>= 1) sq += __shfl_xor(sq, o2, 32);
        if (ln == 0) sqnorm[n] = sq;
    }
    // block-level deg max -> one atomic per wave
    for (int o2 = 32; o2 > 0; o2 >>= 1) dmx = fmaxf(dmx, __shfl_xor(dmx, o2));
    if ((t & 63) == 0) atomicMax(dmax, __float_as_int(dmx)); // nonneg: int cmp ok
}

// ---------------- sensitivity reductions -------------------------------------
__global__ void k_sens1(const int* __restrict__ ndeg, const float* __restrict__ sqnorm,
                        const int* __restrict__ dmax, float* __restrict__ s,
                        int* __restrict__ smax) {
    int i = blockIdx.x * 256 + threadIdx.x;
    float dm = __int_as_float(*dmax);
    float v = 0.f;
    if (i < N_NODES) {
        v = sqrtf(sqnorm[i]) * ((float)ndeg[i] / (dm + EPS));
        s[i] = v;
    }
    for (int o = 32; o > 0; o >>= 1) v = fmaxf(v, __shfl_xor(v, o));
    if ((threadIdx.x & 63) == 0) atomicMax(smax, __float_as_int(v));
}

__global__ void k_sens2(const float* __restrict__ s, const int* __restrict__ smax,
                        float* __restrict__ sens) {
    int i = blockIdx.x * 256 + threadIdx.x;
    if (i < N_NODES) sens[i] = s[i] / (__int_as_float(*smax) + EPS);
}

// -----------------------------------------------------------------------------
extern "C" void kernel_launch(void* const* d_in, const int* in_sizes, int n_in,
                              void* d_out, int out_size, void* d_ws, size_t ws_size,
                              hipStream_t stream) {
    const float* nf  = (const float*)d_in[0];   // (N, C)
    const float* inc = (const float*)d_in[1];   // (N, E)
    const float* W1  = (const float*)d_in[2];   // (C, C)
    const float* b1  = (const float*)d_in[3];   // (C,)
    const float* W2  = (const float*)d_in[4];   // (C, C)
    const float* b2  = (const float*)d_in[5];   // (C,)
    const float* ea  = (const float*)d_in[6];   // (E,)

    float* out = (float*)d_out;
    float* out_node = out;                       // N*C = 12,800,000
    float* out_he   = out + 12800000;            // E*C = 131,072
    float* out_attn = out + 12931072;            // E   = 1,024
    float* out_sens = out + 12932096;            // N   = 100,000
    float* out_ent  = out + 13032096;            // 1

    // workspace layout: counters first so one zero-pass covers them
    int* ws         = (int*)d_ws;
    int* edge_cnt   = ws;                        // 1024
    int* ndeg       = ws + 1024;                 // 100000
    int* dmax       = ws + 101024;               // 1
    int* smax       = ws + 101025;               // 1
    int* edge_nodes = ws + 101040;               // 1024*1280 ints (5.24 MB)
    unsigned short* node_edges = (unsigned short*)(edge_nodes + N_EDGES * EDGE_CAP); // 100000*64 u16 (12.8 MB)
    float* he2      = (float*)(node_edges + N_NODES * NODE_CAP); // 1024*128
    float* sqnorm   = he2 + N_EDGES * C_DIM;     // 100000
    float* s_tmp    = sqnorm + N_NODES;          // 100000
    // total ws: ~20 MB

    const int nchunk = (N_NODES + CHUNK_R - 1) / CHUNK_R;   // 49
    k_zero<<<dim3((101026 + 255) / 256), dim3(256), 0, stream>>>(ws, 101026);
    k_attn_entropy<<<dim3(1), dim3(1024), 0, stream>>>(ea, out_attn, out_ent);
    k_scan<<<dim3(nchunk, N_EDGES / STRIP_W), dim3(256), 0, stream>>>(
        (const float4*)inc, edge_cnt, ndeg, edge_nodes, node_edges);
    k_edge<<<dim3(N_EDGES), dim3(256), 0, stream>>>(
        nf, edge_cnt, edge_nodes, W1, b1, W2, out_attn, out_he, he2);
    k_node<<<dim3((N_NODES + 7) / 8), dim3(256), 0, stream>>>(
        nf, ndeg, node_edges, he2, b2, out_node, sqnorm, dmax);
    k_sens1<<<dim3((N_NODES + 255) / 256), dim3(256), 0, stream>>>(ndeg, sqnorm, dmax, s_tmp, smax);
    k_sens2<<<dim3((N_NODES + 255) / 256), dim3(256), 0, stream>>>(s_tmp, smax, out_sens);
}

// Round 5
// 772.299 us; speedup vs baseline: 1.6492x; 1.6492x over previous
//
#include <hip/hip_runtime.h>

#define N_NODES 100000
#define N_EDGES 1024
#define C_DIM 128
#define EDGE_CAP 1280   // Binom(100000,0.01): mean 1000, sd 31.5 -> +8.9 sigma
#define NODE_CAP 64     // Binom(1024,0.01): mean 10.24 -> +16 sigma
#define STRIP_W 32      // 32 floats = 128 B = one cache line per row-segment
#define CHUNK_R 2048    // rows per block
#define LCAP 64         // per-block per-edge LDS list cap: mean 20.5, +9.7 sigma
#define EPS 1e-8f

// ---------------- zero the counters (ws is re-poisoned to 0xAA every call) ---
__global__ void k_zero(int* p, int n) {
    int i = blockIdx.x * 256 + threadIdx.x;
    if (i < n) p[i] = 0;
}

// ---------------- softmax over edge_attention + entropy (E=1024, 1 block) ---
__global__ void k_attn_entropy(const float* __restrict__ ea,
                               float* __restrict__ attn,
                               float* __restrict__ entropy) {
    __shared__ float red[17];
    int t = threadIdx.x;              // blockDim = 1024 = 16 waves
    float x = ea[t];

    float m = x;
    for (int o = 32; o > 0; o >>= 1) m = fmaxf(m, __shfl_xor(m, o));
    if ((t & 63) == 0) red[t >> 6] = m;
    __syncthreads();
    if (t == 0) { float a = red[0]; for (int i = 1; i < 16; i++) a = fmaxf(a, red[i]); red[16] = a; }
    __syncthreads();
    m = red[16];
    __syncthreads();

    float ex = expf(x - m);
    float s = ex;
    for (int o = 32; o > 0; o >>= 1) s += __shfl_xor(s, o);
    if ((t & 63) == 0) red[t >> 6] = s;
    __syncthreads();
    if (t == 0) { float a = 0; for (int i = 0; i < 16; i++) a += red[i]; red[16] = a; }
    __syncthreads();
    float S = red[16];
    __syncthreads();

    float a_t = ex / S;
    attn[t] = a_t;

    float T = a_t;
    for (int o = 32; o > 0; o >>= 1) T += __shfl_xor(T, o);
    if ((t & 63) == 0) red[t >> 6] = T;
    __syncthreads();
    if (t == 0) { float a = 0; for (int i = 0; i < 16; i++) a += red[i]; red[16] = a; }
    __syncthreads();
    T = red[16];
    __syncthreads();

    float p = a_t / (T + EPS);
    float ent = -p * logf(p + EPS);
    for (int o = 32; o > 0; o >>= 1) ent += __shfl_xor(ent, o);
    if ((t & 63) == 0) red[t >> 6] = ent;
    __syncthreads();
    if (t == 0) { float a = 0; for (int i = 0; i < 16; i++) a += red[i]; entropy[0] = a; }
}

// ------- strip scan: LDS-aggregated CSC build + direct CSR (u16), coalesced --
// grid = (NCHUNK, E/STRIP_W) [chunk-major: concurrent blocks hit different
// node rows]; block = 256. 4-row unrolled loads for memory-level parallelism.
__global__ __launch_bounds__(256) void k_scan(
        const float4* __restrict__ inc4,
        int* __restrict__ edge_cnt, int* __restrict__ ndeg,
        int* __restrict__ edge_nodes, unsigned short* __restrict__ node_edges) {
    __shared__ int lcnt[STRIP_W];
    __shared__ int lbase[STRIP_W];
    __shared__ int llist[STRIP_W * LCAP];
    int t = threadIdx.x;
    int e0 = blockIdx.y * STRIP_W;       // strip's first edge
    int row0 = blockIdx.x * CHUNK_R;
    if (t < STRIP_W) lcnt[t] = 0;
    __syncthreads();

    int rsub = t >> 3;                   // 0..31: row within 32-row group
    int seg  = t & 7;                    // 0..7: float4 within the 32-col strip
    int off  = (e0 >> 2) + seg;
    #pragma unroll 1
    for (int it = 0; it < CHUNK_R / 128; it++) {   // 16 iters x 128 rows
        int rA = row0 + it * 128 + rsub;
        int rB = rA + 32, rC = rA + 64, rD = rA + 96;
        float4 z = {0.f, 0.f, 0.f, 0.f};
        float4 vA = z, vB = z, vC = z, vD = z;
        // 4 independent loads issued before any use -> 4x latency hiding
        if (rA < N_NODES) vA = inc4[(size_t)rA * (N_EDGES / 4) + off];
        if (rB < N_NODES) vB = inc4[(size_t)rB * (N_EDGES / 4) + off];
        if (rC < N_NODES) vC = inc4[(size_t)rC * (N_EDGES / 4) + off];
        if (rD < N_NODES) vD = inc4[(size_t)rD * (N_EDGES / 4) + off];

        float4 vs[4] = {vA, vB, vC, vD};
        int    rs[4] = {rA, rB, rC, rD};
        #pragma unroll
        for (int j = 0; j < 4; j++) {
            float4 v = vs[j];
            int row = rs[j];
            if (v.x != 0.f || v.y != 0.f || v.z != 0.f || v.w != 0.f) {
                float vals[4] = {v.x, v.y, v.z, v.w};
                #pragma unroll
                for (int k = 0; k < 4; k++) {
                    if (vals[k] != 0.0f) {
                        int el = seg * 4 + k;                       // local edge 0..31
                        int p = atomicAdd(&lcnt[el], 1);            // LDS atomic: cheap
                        if (p < LCAP) llist[el * LCAP + p] = row;
                        int q = atomicAdd(&ndeg[row], 1);           // chunk-local rows
                        if (q < NODE_CAP)
                            node_edges[row * NODE_CAP + q] = (unsigned short)(e0 + el);
                    }
                }
            }
        }
    }
    __syncthreads();
    if (t < STRIP_W) {
        int c = lcnt[t];
        if (c > LCAP) { c = LCAP; lcnt[t] = LCAP; }
        lbase[t] = atomicAdd(&edge_cnt[e0 + t], c);   // ONE reservation per edge per block
    }
    __syncthreads();
    // coalesced copy-out of the per-edge lists
    for (int j = t; j < STRIP_W * LCAP; j += 256) {
        int el = j / LCAP;
        int k  = j - el * LCAP;
        if (k < lcnt[el]) {
            int dst = lbase[el] + k;
            if (dst < EDGE_CAP)
                edge_nodes[(e0 + el) * EDGE_CAP + dst] = llist[j];
        }
    }
}

// -------- per-edge: he0 = sum nf rows; he1 = (he0@W1+b1)*attn; he2 = he1@W2 --
__global__ __launch_bounds__(256) void k_edge(
        const float* __restrict__ nf, const int* __restrict__ edge_cnt,
        const int* __restrict__ edge_nodes,
        const float* __restrict__ W1, const float* __restrict__ b1,
        const float* __restrict__ W2, const float* __restrict__ attn,
        float* __restrict__ he_out, float* __restrict__ he2) {
    __shared__ float lds[8 * 128];
    __shared__ float row[128];
    int e = blockIdx.x;
    int t = threadIdx.x;
    int grp = t >> 5, ln = t & 31;       // 8 row-groups x 32 lanes (float4 = 128 ch)
    int cnt = edge_cnt[e]; if (cnt > EDGE_CAP) cnt = EDGE_CAP;
    const int* nl = edge_nodes + e * EDGE_CAP;

    float4 acc = {0.f, 0.f, 0.f, 0.f};
    int i = grp;
    // 4-way unrolled: 4 independent row loads in flight per iteration
    for (; i + 24 < cnt; i += 32) {
        int n0 = nl[i], n1 = nl[i + 8], n2 = nl[i + 16], n3 = nl[i + 24];
        float4 x0 = ((const float4*)(nf + n0 * C_DIM))[ln];
        float4 x1 = ((const float4*)(nf + n1 * C_DIM))[ln];
        float4 x2 = ((const float4*)(nf + n2 * C_DIM))[ln];
        float4 x3 = ((const float4*)(nf + n3 * C_DIM))[ln];
        acc.x += x0.x + x1.x + x2.x + x3.x;
        acc.y += x0.y + x1.y + x2.y + x3.y;
        acc.z += x0.z + x1.z + x2.z + x3.z;
        acc.w += x0.w + x1.w + x2.w + x3.w;
    }
    for (; i < cnt; i += 8) {
        int nd = nl[i];
        float4 x = ((const float4*)(nf + nd * C_DIM))[ln];
        acc.x += x.x; acc.y += x.y; acc.z += x.z; acc.w += x.w;
    }
    ((float4*)lds)[grp * 32 + ln] = acc;
    __syncthreads();
    if (t < 128) {
        float s = 0.f;
        #pragma unroll
        for (int g = 0; g < 8; g++) s += lds[g * 128 + t];
        row[t] = s;                                   // he0[e, t]
    }
    __syncthreads();

    float attn_e = attn[e];
    float h1 = 0.f;
    if (t < 128) {
        float s = b1[t];
        #pragma unroll 8
        for (int c = 0; c < 128; c++) s += row[c] * W1[c * 128 + t];
        h1 = s * attn_e;
        he_out[e * 128 + t] = h1;                     // "he" output (post-attn)
    }
    __syncthreads();
    if (t < 128) row[t] = h1;
    __syncthreads();
    if (t < 128) {
        float s = 0.f;
        #pragma unroll 8
        for (int c = 0; c < 128; c++) s += row[c] * W2[c * 128 + t];
        he2[e * 128 + t] = s;                         // he1 @ W2 (assoc. trick)
    }
}

// -------- per-node: out = sum he2[edges] + b2 + nf (residual); also sqnorm ---
// NOTE: NO single-address atomics here — R4 folded degmax in as one atomicMax
// per wave (50k same-line atomics across the 12.5k-block grid) and k_node went
// 578 us. Degmax lives in its own 391-block kernel below (1.5k atomics).
__global__ __launch_bounds__(256) void k_node(
        const float* __restrict__ nf, const int* __restrict__ ndeg,
        const unsigned short* __restrict__ node_edges, const float* __restrict__ he2,
        const float* __restrict__ b2,
        float* __restrict__ out_node, float* __restrict__ sqnorm) {
    int t = threadIdx.x;
    int nsub = t >> 5, ln = t & 31;       // 8 nodes/block, 32 lanes * float4
    int n = blockIdx.x * 8 + nsub;
    if (n >= N_NODES) return;
    int d = ndeg[n]; if (d > NODE_CAP) d = NODE_CAP;
    const unsigned short* el = node_edges + n * NODE_CAP;

    float4 acc = {0.f, 0.f, 0.f, 0.f};
    for (int i = 0; i < d; i++) {
        int e = (int)el[i];
        float4 h = ((const float4*)(he2 + e * C_DIM))[ln];
        acc.x += h.x; acc.y += h.y; acc.z += h.z; acc.w += h.w;
    }
    float4 x  = ((const float4*)(nf + n * C_DIM))[ln];
    float4 bb = ((const float4*)b2)[ln];
    float4 o = {acc.x + bb.x + x.x, acc.y + bb.y + x.y,
                acc.z + bb.z + x.z, acc.w + bb.w + x.w};
    ((float4*)(out_node + n * C_DIM))[ln] = o;

    float sq = x.x * x.x + x.y * x.y + x.z * x.z + x.w * x.w;
    for (int o2 = 16; o2 > 0; o2 >>= 1) sq += __shfl_xor(sq, o2, 32);
    if (ln == 0) sqnorm[n] = sq;
}

// ---------------- sensitivity reductions -------------------------------------
__global__ void k_degmax(const int* __restrict__ ndeg, int* __restrict__ dmax) {
    int i = blockIdx.x * 256 + threadIdx.x;
    float v = (i < N_NODES) ? (float)ndeg[i] : 0.f;
    for (int o = 32; o > 0; o >>= 1) v = fmaxf(v, __shfl_xor(v, o));
    if ((threadIdx.x & 63) == 0) atomicMax(dmax, __float_as_int(v)); // nonneg floats: int cmp ok
}

__global__ void k_sens1(const int* __restrict__ ndeg, const float* __restrict__ sqnorm,
                        const int* __restrict__ dmax, float* __restrict__ s,
                        int* __restrict__ smax) {
    int i = blockIdx.x * 256 + threadIdx.x;
    float dm = __int_as_float(*dmax);
    float v = 0.f;
    if (i < N_NODES) {
        v = sqrtf(sqnorm[i]) * ((float)ndeg[i] / (dm + EPS));
        s[i] = v;
    }
    for (int o = 32; o > 0; o >>= 1) v = fmaxf(v, __shfl_xor(v, o));
    if ((threadIdx.x & 63) == 0) atomicMax(smax, __float_as_int(v));
}

__global__ void k_sens2(const float* __restrict__ s, const int* __restrict__ smax,
                        float* __restrict__ sens) {
    int i = blockIdx.x * 256 + threadIdx.x;
    if (i < N_NODES) sens[i] = s[i] / (__int_as_float(*smax) + EPS);
}

// -----------------------------------------------------------------------------
extern "C" void kernel_launch(void* const* d_in, const int* in_sizes, int n_in,
                              void* d_out, int out_size, void* d_ws, size_t ws_size,
                              hipStream_t stream) {
    const float* nf  = (const float*)d_in[0];   // (N, C)
    const float* inc = (const float*)d_in[1];   // (N, E)
    const float* W1  = (const float*)d_in[2];   // (C, C)
    const float* b1  = (const float*)d_in[3];   // (C,)
    const float* W2  = (const float*)d_in[4];   // (C, C)
    const float* b2  = (const float*)d_in[5];   // (C,)
    const float* ea  = (const float*)d_in[6];   // (E,)

    float* out = (float*)d_out;
    float* out_node = out;                       // N*C = 12,800,000
    float* out_he   = out + 12800000;            // E*C = 131,072
    float* out_attn = out + 12931072;            // E   = 1,024
    float* out_sens = out + 12932096;            // N   = 100,000
    float* out_ent  = out + 13032096;            // 1

    // workspace layout: counters first so one zero-pass covers them
    int* ws         = (int*)d_ws;
    int* edge_cnt   = ws;                        // 1024
    int* ndeg       = ws + 1024;                 // 100000
    int* dmax       = ws + 101024;               // 1
    int* smax       = ws + 101025;               // 1
    int* edge_nodes = ws + 101040;               // 1024*1280 ints (5.24 MB)
    unsigned short* node_edges = (unsigned short*)(edge_nodes + N_EDGES * EDGE_CAP); // 100000*64 u16 (12.8 MB)
    float* he2      = (float*)(node_edges + N_NODES * NODE_CAP); // 1024*128
    float* sqnorm   = he2 + N_EDGES * C_DIM;     // 100000
    float* s_tmp    = sqnorm + N_NODES;          // 100000
    // total ws: ~20 MB

    const int nchunk = (N_NODES + CHUNK_R - 1) / CHUNK_R;   // 49
    k_zero<<<dim3((101026 + 255) / 256), dim3(256), 0, stream>>>(ws, 101026);
    k_attn_entropy<<<dim3(1), dim3(1024), 0, stream>>>(ea, out_attn, out_ent);
    k_scan<<<dim3(nchunk, N_EDGES / STRIP_W), dim3(256), 0, stream>>>(
        (const float4*)inc, edge_cnt, ndeg, edge_nodes, node_edges);
    k_degmax<<<dim3((N_NODES + 255) / 256), dim3(256), 0, stream>>>(ndeg, dmax);
    k_edge<<<dim3(N_EDGES), dim3(256), 0, stream>>>(
        nf, edge_cnt, edge_nodes, W1, b1, W2, out_attn, out_he, he2);
    k_node<<<dim3((N_NODES + 7) / 8), dim3(256), 0, stream>>>(
        nf, ndeg, node_edges, he2, b2, out_node, sqnorm);
    k_sens1<<<dim3((N_NODES + 255) / 256), dim3(256), 0, stream>>>(ndeg, sqnorm, dmax, s_tmp, smax);
    k_sens2<<<dim3((N_NODES + 255) / 256), dim3(256), 0, stream>>>(s_tmp, smax, out_sens);
}

// Round 6
// 750.161 us; speedup vs baseline: 1.6979x; 1.0295x over previous
//
#include <hip/hip_runtime.h>

#define N_NODES 100000
#define N_EDGES 1024
#define C_DIM 128
#define EDGE_CAP 1280   // Binom(100000,0.01): mean 1000, sd 31.5 -> +8.9 sigma
#define NODE_CAP 64     // Binom(1024,0.01): mean 10.24 -> +16 sigma
#define STRIP_W 32      // 32 floats = 128 B = one cache line per row-segment
#define CHUNK_R 2048    // rows per block
#define LCAP 64         // per-block per-edge LDS list cap: mean 20.5, +9.7 sigma
#define EPS 1e-8f

// ---------------- zero the counters (ws is re-poisoned to 0xAA every call) ---
__global__ void k_zero(int* p, int n) {
    int i = blockIdx.x * 256 + threadIdx.x;
    if (i < n) p[i] = 0;
}

// ---------------- softmax over edge_attention + entropy (E=1024, 1 block) ---
__global__ void k_attn_entropy(const float* __restrict__ ea,
                               float* __restrict__ attn,
                               float* __restrict__ entropy) {
    __shared__ float red[17];
    int t = threadIdx.x;              // blockDim = 1024 = 16 waves
    float x = ea[t];

    float m = x;
    for (int o = 32; o > 0; o >>= 1) m = fmaxf(m, __shfl_xor(m, o));
    if ((t & 63) == 0) red[t >> 6] = m;
    __syncthreads();
    if (t == 0) { float a = red[0]; for (int i = 1; i < 16; i++) a = fmaxf(a, red[i]); red[16] = a; }
    __syncthreads();
    m = red[16];
    __syncthreads();

    float ex = expf(x - m);
    float s = ex;
    for (int o = 32; o > 0; o >>= 1) s += __shfl_xor(s, o);
    if ((t & 63) == 0) red[t >> 6] = s;
    __syncthreads();
    if (t == 0) { float a = 0; for (int i = 0; i < 16; i++) a += red[i]; red[16] = a; }
    __syncthreads();
    float S = red[16];
    __syncthreads();

    float a_t = ex / S;
    attn[t] = a_t;

    float T = a_t;
    for (int o = 32; o > 0; o >>= 1) T += __shfl_xor(T, o);
    if ((t & 63) == 0) red[t >> 6] = T;
    __syncthreads();
    if (t == 0) { float a = 0; for (int i = 0; i < 16; i++) a += red[i]; red[16] = a; }
    __syncthreads();
    T = red[16];
    __syncthreads();

    float p = a_t / (T + EPS);
    float ent = -p * logf(p + EPS);
    for (int o = 32; o > 0; o >>= 1) ent += __shfl_xor(ent, o);
    if ((t & 63) == 0) red[t >> 6] = ent;
    __syncthreads();
    if (t == 0) { float a = 0; for (int i = 0; i < 16; i++) a += red[i]; entropy[0] = a; }
}

// ------- strip scan: CSC via LDS lists + CSR via presence BITMASKS ----------
// grid = (NCHUNK, E/STRIP_W); block = 256. Each block exclusively owns
// (strip, rows r0..r0+2047): masks[strip][row] written with plain stores —
// NO global atomics anywhere in this kernel (R5 showed the ndeg atomic
// round-trip + u16 scatter was the scan's overhead over the HBM floor).
__global__ __launch_bounds__(256) void k_scan(
        const float4* __restrict__ inc4,
        int* __restrict__ edge_cnt,
        unsigned int* __restrict__ masks,      // [STRIP][N_NODES]
        int* __restrict__ edge_nodes) {
    __shared__ int lcnt[STRIP_W];
    __shared__ int lbase[STRIP_W];
    __shared__ int llist[STRIP_W * LCAP];
    int t = threadIdx.x;
    int strip = blockIdx.y;
    int e0 = strip * STRIP_W;
    int row0 = blockIdx.x * CHUNK_R;
    if (t < STRIP_W) lcnt[t] = 0;
    __syncthreads();

    int rsub = t >> 3;                   // 0..31: row within 128-row group
    int seg  = t & 7;                    // 0..7: float4 within the 32-col strip
    int off  = (e0 >> 2) + seg;
    #pragma unroll 1
    for (int it = 0; it < CHUNK_R / 128; it++) {   // 16 iters x 128 rows
        int rA = row0 + it * 128 + rsub;
        int rB = rA + 32, rC = rA + 64, rD = rA + 96;
        float4 z = {0.f, 0.f, 0.f, 0.f};
        float4 vA = z, vB = z, vC = z, vD = z;
        if (rA < N_NODES) vA = inc4[(size_t)rA * (N_EDGES / 4) + off];
        if (rB < N_NODES) vB = inc4[(size_t)rB * (N_EDGES / 4) + off];
        if (rC < N_NODES) vC = inc4[(size_t)rC * (N_EDGES / 4) + off];
        if (rD < N_NODES) vD = inc4[(size_t)rD * (N_EDGES / 4) + off];

        float4 vs[4] = {vA, vB, vC, vD};
        int    rs[4] = {rA, rB, rC, rD};
        #pragma unroll
        for (int j = 0; j < 4; j++) {
            float4 v = vs[j];
            int row = rs[j];
            unsigned nib = (v.x != 0.f ? 1u : 0u) | (v.y != 0.f ? 2u : 0u)
                         | (v.z != 0.f ? 4u : 0u) | (v.w != 0.f ? 8u : 0u);
            // assemble 32-bit strip mask across the 8 seg-lanes (same wave)
            unsigned word = nib << (seg * 4);
            word |= __shfl_xor((int)word, 1);
            word |= __shfl_xor((int)word, 2);
            word |= __shfl_xor((int)word, 4);
            if (seg == 0 && row < N_NODES)
                masks[(size_t)strip * N_NODES + row] = word;   // exclusive owner
            // CSC: each lane expands only its own 4 columns (no duplicates)
            while (nib) {
                int k = __ffs(nib) - 1; nib &= nib - 1;
                int el = seg * 4 + k;                       // local edge 0..31
                int p = atomicAdd(&lcnt[el], 1);            // LDS atomic: cheap
                if (p < LCAP) llist[el * LCAP + p] = row;
            }
        }
    }
    __syncthreads();
    if (t < STRIP_W) {
        int c = lcnt[t];
        if (c > LCAP) { c = LCAP; lcnt[t] = LCAP; }
        lbase[t] = atomicAdd(&edge_cnt[e0 + t], c);   // ONE reservation per edge per block
    }
    __syncthreads();
    // coalesced copy-out of the per-edge lists
    for (int j = t; j < STRIP_W * LCAP; j += 256) {
        int el = j / LCAP;
        int k  = j - el * LCAP;
        if (k < lcnt[el]) {
            int dst = lbase[el] + k;
            if (dst < EDGE_CAP)
                edge_nodes[(e0 + el) * EDGE_CAP + dst] = llist[j];
        }
    }
}

// -------- per-edge: he0 = sum nf rows; he1 = (he0@W1+b1)*attn; he2 = he1@W2 --
__global__ __launch_bounds__(256) void k_edge(
        const float* __restrict__ nf, const int* __restrict__ edge_cnt,
        const int* __restrict__ edge_nodes,
        const float* __restrict__ W1, const float* __restrict__ b1,
        const float* __restrict__ W2, const float* __restrict__ attn,
        float* __restrict__ he_out, float* __restrict__ he2) {
    __shared__ float lds[8 * 128];
    __shared__ float row[128];
    int e = blockIdx.x;
    int t = threadIdx.x;
    int grp = t >> 5, ln = t & 31;       // 8 row-groups x 32 lanes (float4 = 128 ch)
    int cnt = edge_cnt[e]; if (cnt > EDGE_CAP) cnt = EDGE_CAP;
    const int* nl = edge_nodes + e * EDGE_CAP;

    float4 acc = {0.f, 0.f, 0.f, 0.f};
    int i = grp;
    // 4-way unrolled: 4 independent row loads in flight per iteration
    for (; i + 24 < cnt; i += 32) {
        int n0 = nl[i], n1 = nl[i + 8], n2 = nl[i + 16], n3 = nl[i + 24];
        float4 x0 = ((const float4*)(nf + n0 * C_DIM))[ln];
        float4 x1 = ((const float4*)(nf + n1 * C_DIM))[ln];
        float4 x2 = ((const float4*)(nf + n2 * C_DIM))[ln];
        float4 x3 = ((const float4*)(nf + n3 * C_DIM))[ln];
        acc.x += x0.x + x1.x + x2.x + x3.x;
        acc.y += x0.y + x1.y + x2.y + x3.y;
        acc.z += x0.z + x1.z + x2.z + x3.z;
        acc.w += x0.w + x1.w + x2.w + x3.w;
    }
    for (; i < cnt; i += 8) {
        int nd = nl[i];
        float4 x = ((const float4*)(nf + nd * C_DIM))[ln];
        acc.x += x.x; acc.y += x.y; acc.z += x.z; acc.w += x.w;
    }
    ((float4*)lds)[grp * 32 + ln] = acc;
    __syncthreads();
    if (t < 128) {
        float s = 0.f;
        #pragma unroll
        for (int g = 0; g < 8; g++) s += lds[g * 128 + t];
        row[t] = s;                                   // he0[e, t]
    }
    __syncthreads();

    float attn_e = attn[e];
    float h1 = 0.f;
    if (t < 128) {
        float s = b1[t];
        #pragma unroll 8
        for (int c = 0; c < 128; c++) s += row[c] * W1[c * 128 + t];
        h1 = s * attn_e;
        he_out[e * 128 + t] = h1;                     // "he" output (post-attn)
    }
    __syncthreads();
    if (t < 128) row[t] = h1;
    __syncthreads();
    if (t < 128) {
        float s = 0.f;
        #pragma unroll 8
        for (int c = 0; c < 128; c++) s += row[c] * W2[c * 128 + t];
        he2[e * 128 + t] = s;                         // he1 @ W2 (assoc. trick)
    }
}

// -------- per-node: rebuild edge list from masks (in LDS), out = sum he2 +
//          b2 + nf; also writes ndeg (int) and sqnorm. NO global atomics. ----
// grid = 12500 blocks x 256 thr; 8 nodes/block (exactly 100000).
__global__ __launch_bounds__(256) void k_node(
        const float* __restrict__ nf, const unsigned int* __restrict__ masks,
        const float* __restrict__ he2, const float* __restrict__ b2,
        float* __restrict__ out_node, float* __restrict__ sqnorm,
        int* __restrict__ ndeg) {
    __shared__ int elist[8 * NODE_CAP];
    __shared__ int ndeg_s[8];
    int t = threadIdx.x;

    // ---- phase 1: thread t = (node_local nl_)*32 + strip; parse masks ----
    {
        int nl_ = t >> 5, st = t & 31;
        int n = blockIdx.x * 8 + nl_;
        unsigned mask = 0;
        if (n < N_NODES) mask = masks[(size_t)st * N_NODES + n];
        int pc = __popc(mask);
        int pre = pc;                       // inclusive prefix over 32-lane group
        #pragma unroll
        for (int o = 1; o < 32; o <<= 1) {
            int v = __shfl_up(pre, o, 32);
            if (st >= o) pre += v;
        }
        int base = pre - pc;                // exclusive prefix
        unsigned m = mask; int r = 0;
        while (m) {
            int b = __ffs(m) - 1; m &= m - 1;
            int idx = base + r;
            if (idx < NODE_CAP) elist[nl_ * NODE_CAP + idx] = st * 32 + b;
            r++;
        }
        if (st == 31) {
            int tot = pre;
            if (n < N_NODES) ndeg[n] = tot;         // true degree
            if (tot > NODE_CAP) tot = NODE_CAP;
            ndeg_s[nl_] = tot;
        }
    }
    __syncthreads();

    // ---- phase 2: 8 nodes x 32 lanes x float4 channels ----
    int nsub = t >> 5, ln = t & 31;
    int n = blockIdx.x * 8 + nsub;
    if (n >= N_NODES) return;
    int d = ndeg_s[nsub];
    const int* el = elist + nsub * NODE_CAP;

    float4 acc = {0.f, 0.f, 0.f, 0.f};
    int i = 0;
    for (; i + 3 < d; i += 4) {          // 4 independent he2-row loads in flight
        int e0 = el[i], e1 = el[i + 1], e2 = el[i + 2], e3 = el[i + 3];
        float4 h0 = ((const float4*)(he2 + e0 * C_DIM))[ln];
        float4 h1 = ((const float4*)(he2 + e1 * C_DIM))[ln];
        float4 h2 = ((const float4*)(he2 + e2 * C_DIM))[ln];
        float4 h3 = ((const float4*)(he2 + e3 * C_DIM))[ln];
        acc.x += h0.x + h1.x + h2.x + h3.x;
        acc.y += h0.y + h1.y + h2.y + h3.y;
        acc.z += h0.z + h1.z + h2.z + h3.z;
        acc.w += h0.w + h1.w + h2.w + h3.w;
    }
    for (; i < d; i++) {
        int e = el[i];
        float4 h = ((const float4*)(he2 + e * C_DIM))[ln];
        acc.x += h.x; acc.y += h.y; acc.z += h.z; acc.w += h.w;
    }
    float4 x  = ((const float4*)(nf + n * C_DIM))[ln];
    float4 bb = ((const float4*)b2)[ln];
    float4 o = {acc.x + bb.x + x.x, acc.y + bb.y + x.y,
                acc.z + bb.z + x.z, acc.w + bb.w + x.w};
    ((float4*)(out_node + n * C_DIM))[ln] = o;

    float sq = x.x * x.x + x.y * x.y + x.z * x.z + x.w * x.w;
    for (int o2 = 16; o2 > 0; o2 >>= 1) sq += __shfl_xor(sq, o2, 32);
    if (ln == 0) sqnorm[n] = sq;
}

// ---------------- sensitivity reductions (AFTER k_node: ndeg source) ---------
__global__ void k_degmax(const int* __restrict__ ndeg, int* __restrict__ dmax) {
    int i = blockIdx.x * 256 + threadIdx.x;
    float v = (i < N_NODES) ? (float)ndeg[i] : 0.f;
    for (int o = 32; o > 0; o >>= 1) v = fmaxf(v, __shfl_xor(v, o));
    if ((threadIdx.x & 63) == 0) atomicMax(dmax, __float_as_int(v)); // nonneg floats: int cmp ok
}

__global__ void k_sens1(const int* __restrict__ ndeg, const float* __restrict__ sqnorm,
                        const int* __restrict__ dmax, float* __restrict__ s,
                        int* __restrict__ smax) {
    int i = blockIdx.x * 256 + threadIdx.x;
    float dm = __int_as_float(*dmax);
    float v = 0.f;
    if (i < N_NODES) {
        v = sqrtf(sqnorm[i]) * ((float)ndeg[i] / (dm + EPS));
        s[i] = v;
    }
    for (int o = 32; o > 0; o >>= 1) v = fmaxf(v, __shfl_xor(v, o));
    if ((threadIdx.x & 63) == 0) atomicMax(smax, __float_as_int(v));
}

__global__ void k_sens2(const float* __restrict__ s, const int* __restrict__ smax,
                        float* __restrict__ sens) {
    int i = blockIdx.x * 256 + threadIdx.x;
    if (i < N_NODES) sens[i] = s[i] / (__int_as_float(*smax) + EPS);
}

// -----------------------------------------------------------------------------
extern "C" void kernel_launch(void* const* d_in, const int* in_sizes, int n_in,
                              void* d_out, int out_size, void* d_ws, size_t ws_size,
                              hipStream_t stream) {
    const float* nf  = (const float*)d_in[0];   // (N, C)
    const float* inc = (const float*)d_in[1];   // (N, E)
    const float* W1  = (const float*)d_in[2];   // (C, C)
    const float* b1  = (const float*)d_in[3];   // (C,)
    const float* W2  = (const float*)d_in[4];   // (C, C)
    const float* b2  = (const float*)d_in[5];   // (C,)
    const float* ea  = (const float*)d_in[6];   // (E,)

    float* out = (float*)d_out;
    float* out_node = out;                       // N*C = 12,800,000
    float* out_he   = out + 12800000;            // E*C = 131,072
    float* out_attn = out + 12931072;            // E   = 1,024
    float* out_sens = out + 12932096;            // N   = 100,000
    float* out_ent  = out + 13032096;            // 1

    // workspace layout: only edge_cnt/dmax/smax need zeroing (1026 ints);
    // masks and ndeg are fully overwritten each call.
    int* ws         = (int*)d_ws;
    int* edge_cnt   = ws;                        // 1024
    int* dmax       = ws + 1024;                 // 1
    int* smax       = ws + 1025;                 // 1
    int* ndeg       = ws + 1028;                 // 100000 (written by k_node)
    unsigned int* masks = (unsigned int*)(ws + 101028);   // 32*100000 (12.8 MB)
    int* edge_nodes = (int*)(masks + (size_t)STRIP_W * N_NODES); // 1024*1280 (5.24 MB)
    float* he2      = (float*)(edge_nodes + N_EDGES * EDGE_CAP); // 1024*128
    float* sqnorm   = he2 + N_EDGES * C_DIM;     // 100000
    float* s_tmp    = sqnorm + N_NODES;          // 100000
    // total ws: ~20 MB

    const int nchunk = (N_NODES + CHUNK_R - 1) / CHUNK_R;   // 49
    k_zero<<<dim3(5), dim3(256), 0, stream>>>(ws, 1026);
    k_attn_entropy<<<dim3(1), dim3(1024), 0, stream>>>(ea, out_attn, out_ent);
    k_scan<<<dim3(nchunk, N_EDGES / STRIP_W), dim3(256), 0, stream>>>(
        (const float4*)inc, edge_cnt, masks, edge_nodes);
    k_edge<<<dim3(N_EDGES), dim3(256), 0, stream>>>(
        nf, edge_cnt, edge_nodes, W1, b1, W2, out_attn, out_he, he2);
    k_node<<<dim3(N_NODES / 8), dim3(256), 0, stream>>>(
        nf, masks, he2, b2, out_node, sqnorm, ndeg);
    k_degmax<<<dim3((N_NODES + 255) / 256), dim3(256), 0, stream>>>(ndeg, dmax);
    k_sens1<<<dim3((N_NODES + 255) / 256), dim3(256), 0, stream>>>(ndeg, sqnorm, dmax, s_tmp, smax);
    k_sens2<<<dim3((N_NODES + 255) / 256), dim3(256), 0, stream>>>(s_tmp, smax, out_sens);
}